// Round 16
// baseline (320.537 us; speedup 1.0000x reference)
//
#include <hip/hip_runtime.h>

#define P_PIX 22500
#define HB 61
#define HSP 45
#define PPB 512
#define NCHK 4

typedef float f32x4 __attribute__((ext_vector_type(4)));
typedef _Float16 f16x8 __attribute__((ext_vector_type(8)));
typedef _Float16 f16x4 __attribute__((ext_vector_type(4)));

// one-instruction f32 pair -> packed f16x2 (RTZ), as raw u32
static __device__ __forceinline__ unsigned pk2(float a, float b)
{
    return __builtin_bit_cast(unsigned, __builtin_amdgcn_cvt_pkrtz(a, b));
}

// raw v_exp_f32: computes 2^x (ISA: D=2^S0)
static __device__ __forceinline__ float exp2_hw(float x)
{
    return __builtin_amdgcn_exp2f(x);
}

// ---------------------------------------------------------------------------
// MFMA RGB-uv soft histogram (r22, verified — part of 305.2us session best).
// Ladder: exp2 folded constant + cvt_pkrtz packs (r19), weight folded into
// exponent + B_lds dbuf 1-barrier/chunk (r21), HSP=45 TLP (r22).
// REJECTED by measurement: atomic epilogue (r23: +62us), single-buffer LDS
// + wide conv K-chunks (r25: noise), last-block tail fusion (r26: +10us).
// ---------------------------------------------------------------------------
__global__ __launch_bounds__(256) void hist_mfma(
    const float* __restrict__ img, const float* __restrict__ su,
    const float* __restrict__ sv, const float* __restrict__ cw,
    const float* __restrict__ msc, float* __restrict__ hpart)
{
    const int bc = blockIdx.x;
    const int b = bc / 3, c = bc % 3;
    const int split = blockIdx.y;
    const int tid  = threadIdx.x;
    const int wv   = tid >> 6;
    const int lane = tid & 63;
    const int quad = lane >> 4;
    const int mr   = lane & 15;

    __shared__ __align__(16) _Float16 B_lds[2][8192]; // 2 x 16 KB, dbuf
    __shared__ __align__(16) float su_l[PPB];         // staged log-chroma u
    __shared__ __align__(16) float sv_l[PPB];         // staged log-chroma v
    __shared__ __align__(16) float lw_l[PPB];         // staged log2(Iy*c)

    const float sig_u = su[c], sig_v = sv[c];
    const float L2E = 1.4426950408889634f;
    const float c1u = -L2E / (sig_u * sig_u);
    const float c1v = -L2E / (sig_v * sig_v);
    const float cwc = cw[c];
    const float ubin_b = -3.f + 0.1f * (float)lane;
    const float ubin_a = -3.f + 0.1f * (float)(wv * 16 + mr);

    const bool hasM = (msc != nullptr);
    float m00=0,m01=0,m02=0,m10=0,m11=0,m12=0,m20=0,m21=0,m22=0;
    if (hasM) {
        const float* mp = msc + b * 9;
        m00=mp[0]; m01=mp[1]; m02=mp[2];
        m10=mp[3]; m11=mp[4]; m12=mp[5];
        m20=mp[6]; m21=mp[7]; m22=mp[8];
    }

    const int p0 = split * PPB;

    // ---- phase 0: stage all PPB pixels (coalesced, all 256 threads) ----
    for (int i = tid; i < PPB; i += 256) {
        int px = p0 + i;
        float u = 0.f, v = 0.f, wgt = 0.f;
        if (px < P_PIX) {
            const float* ip = img + (size_t)b * 3 * P_PIX + px;
            float r = ip[0], g = ip[P_PIX], bl = ip[2 * P_PIX];
            if (hasM) {
                float r2 = m00 * r + m01 * g + m02 * bl;
                float g2 = m10 * r + m11 * g + m12 * bl;
                float b2 = m20 * r + m21 * g + m22 * bl;
                r = r2; g = g2; bl = b2;
            }
            r  = fminf(fmaxf(r, 0.f), 1.f);
            g  = fminf(fmaxf(g, 0.f), 1.f);
            bl = fminf(fmaxf(bl, 0.f), 1.f);
            float Iy = sqrtf(r * r + g * g + bl * bl);
            float lr = __logf(r + 1e-6f);
            float lg = __logf(g + 1e-6f);
            float lb = __logf(bl + 1e-6f);
            if (c == 0)      { u = lr - lg; v = lr - lb; }
            else if (c == 1) { u = lg - lr; v = lg - lb; }
            else             { u = lb - lr; v = lb - lg; }
            wgt = Iy * cwc;
        }
        su_l[i] = u; sv_l[i] = v;
        lw_l[i] = __log2f(wgt);   // wgt=0 (incl. px out of range) -> -inf -> exp2 = 0
    }
    __syncthreads();

    f32x4 acc[4];
#pragma unroll
    for (int nt = 0; nt < 4; ++nt) acc[nt] = (f32x4){0.f, 0.f, 0.f, 0.f};

    for (int chunk = 0; chunk < NCHK; ++chunk) {
        const float* suc = &su_l[chunk * 128];
        const float* svc = &sv_l[chunk * 128];
        const float* lwc = &lw_l[chunk * 128];
        _Float16* Bbuf = &B_lds[chunk & 1][0];

        // B tile: v-kernel exps -> LDS (f16), double-buffered
#pragma unroll
        for (int r = 0; r < 4; ++r) {
            int pg = wv + 4 * r;
            f32x4 v0 = *(const f32x4*)&svc[pg * 8];
            f32x4 v1 = *(const f32x4*)&svc[pg * 8 + 4];
            float e[8];
#pragma unroll
            for (int j = 0; j < 4; ++j) {
                float d0 = v0[j] - ubin_b;
                e[j] = exp2_hw((d0 * c1v) * d0);
                float d1 = v1[j] - ubin_b;
                e[4 + j] = exp2_hw((d1 * c1v) * d1);
            }
            union { f16x8 h; unsigned w[4]; } bv;
            bv.w[0] = pk2(e[0], e[1]);
            bv.w[1] = pk2(e[2], e[3]);
            bv.w[2] = pk2(e[4], e[5]);
            bv.w[3] = pk2(e[6], e[7]);
            *(f16x8*)&Bbuf[(pg * 64 + lane) * 8] = bv.h;
        }
        // A fragments: u-kernel exps with weight folded into exponent
        f16x8 af[4];
#pragma unroll
        for (int kk = 0; kk < 4; ++kk) {
            int pxg = kk * 4 + quad;
            f32x4 u0 = *(const f32x4*)&suc[pxg * 8];
            f32x4 u1 = *(const f32x4*)&suc[pxg * 8 + 4];
            f32x4 l0 = *(const f32x4*)&lwc[pxg * 8];
            f32x4 l1 = *(const f32x4*)&lwc[pxg * 8 + 4];
            float e[8];
#pragma unroll
            for (int j = 0; j < 4; ++j) {
                float d0 = u0[j] - ubin_a;
                e[j] = exp2_hw(__builtin_fmaf(d0 * c1u, d0, l0[j]));
                float d1 = u1[j] - ubin_a;
                e[4 + j] = exp2_hw(__builtin_fmaf(d1 * c1u, d1, l1[j]));
            }
            union { f16x8 h; unsigned w[4]; } av;
            av.w[0] = pk2(e[0], e[1]);
            av.w[1] = pk2(e[2], e[3]);
            av.w[2] = pk2(e[4], e[5]);
            av.w[3] = pk2(e[6], e[7]);
            af[kk] = av.h;
        }
        __syncthreads();
#pragma unroll
        for (int kk = 0; kk < 4; ++kk) {
            int pgq = kk * 4 + quad;
#pragma unroll
            for (int nt = 0; nt < 4; ++nt) {
                f16x8 bvv = *(const f16x8*)&Bbuf[(pgq * 64 + nt * 16 + mr) * 8];
                acc[nt] = __builtin_amdgcn_mfma_f32_16x16x32_f16(af[kk], bvv, acc[nt], 0, 0, 0);
            }
        }
        // no trailing barrier: dbuf — buffer k rewritten only at k+2, which
        // is separated from MFMA(k) by barrier(k+1).
    }

    float* hp = hpart + ((size_t)bc * HSP + split) * 4096;
#pragma unroll
    for (int nt = 0; nt < 4; ++nt) {
        int v = nt * 16 + mr;
#pragma unroll
        for (int r = 0; r < 4; ++r) {
            int u = wv * 16 + quad * 4 + r;
            hp[u * 64 + v] = acc[nt][r];
        }
    }
}

// ---------------------------------------------------------------------------
// Sum HSP slabs -> hist; per-(b,c) total -> hsum3.
// r28: grid (48,16) = 768 blocks (3/CU), 1 bin/thread. Per-bin slab sum
// order unchanged -> bit-identical.
// ---------------------------------------------------------------------------
__global__ __launch_bounds__(256) void reduce_hist(
    const float* __restrict__ hpart, float* __restrict__ hist,
    float* __restrict__ hsum3)
{
    const int bc = blockIdx.x;
    const int part = blockIdx.y;
    const int tid = threadIdx.x;
    const float* base = hpart + (size_t)bc * HSP * 4096;
    float lsum = 0.f;
    {
        int idx = part * 256 + tid;
        int u = idx >> 6, v = idx & 63;
        float s = 0.f;
        for (int sp = 0; sp < HSP; ++sp) s += base[sp * 4096 + idx];
        if (u < HB && v < HB) {
            hist[(size_t)bc * (HB * HB) + u * HB + v] = s;
            lsum += s;
        }
    }
    __shared__ float red[4];
    for (int off = 32; off; off >>= 1) lsum += __shfl_down(lsum, off, 64);
    if ((tid & 63) == 0) red[tid >> 6] = lsum;
    __syncthreads();
    if (tid == 0) atomicAdd(&hsum3[bc], red[0] + red[1] + red[2] + red[3]);
}

// ---------------------------------------------------------------------------
// conv1 implicit-GEMM MFMA, NHWC output — r27: M-tile 32, grid (16,27)=432
// blocks. (verified −3.2us in r27)
// ---------------------------------------------------------------------------
__global__ __launch_bounds__(256) void conv1_mfma(
    const float* __restrict__ hist, const float* __restrict__ hsum3,
    const _Float16* __restrict__ w1h, const float* __restrict__ bias,
    _Float16* __restrict__ out)
{
    const int b    = blockIdx.x;
    const int m0   = blockIdx.y * 32;
    const int tid  = threadIdx.x;
    const int wv   = tid >> 6;
    const int lane = tid & 63;
    const int quad = lane >> 4;
    const int mr   = lane & 15;

    __shared__ __align__(16) _Float16 A_lds[32 * 96];

    const float sc = 1.f / (hsum3[b * 3] + hsum3[b * 3 + 1] + hsum3[b * 3 + 2] + 1e-6f);
    const float* inb = hist + (size_t)b * 3 * 3721;

    for (int slot = tid; slot < 384; slot += 256) {
        int m  = slot & 31;
        int kg = slot >> 5;
        int mg = m0 + m;
        bool mok = (mg < 841);
        int oh = mok ? mg / 29 : 0;
        int ow = mok ? mg % 29 : 0;
        const float* pbase = inb + (oh * 2) * 61 + (ow * 2);
        f16x8 av;
#pragma unroll
        for (int j = 0; j < 8; ++j) {
            int k = kg * 8 + j;
            float x = 0.f;
            if (mok && k < 75) {
                int ci = k / 25, r = k % 25;
                int kh = r / 5, kw = r % 5;
                x = pbase[ci * 3721 + kh * 61 + kw] * sc;
            }
            av[j] = (_Float16)x;
        }
        *(f16x8*)&A_lds[(kg * 32 + m) * 8] = av;
    }
    __syncthreads();

    f16x8 wf[3][2];
#pragma unroll
    for (int ks = 0; ks < 3; ++ks)
#pragma unroll
        for (int nt = 0; nt < 2; ++nt) {
            int co = (wv * 2 + nt) * 16 + mr;
            wf[ks][nt] = *(const f16x8*)&w1h[co * 96 + ks * 32 + quad * 8];
        }

    f32x4 acc[2][2];
#pragma unroll
    for (int mt = 0; mt < 2; ++mt)
#pragma unroll
        for (int nt = 0; nt < 2; ++nt) acc[mt][nt] = (f32x4){0.f, 0.f, 0.f, 0.f};

#pragma unroll
    for (int ks = 0; ks < 3; ++ks)
#pragma unroll
        for (int mt = 0; mt < 2; ++mt) {
            f16x8 bv = *(const f16x8*)&A_lds[((ks * 4 + quad) * 32 + mt * 16 + mr) * 8];
#pragma unroll
            for (int nt = 0; nt < 2; ++nt)
                acc[mt][nt] = __builtin_amdgcn_mfma_f32_16x16x32_f16(bv, wf[ks][nt], acc[mt][nt], 0, 0, 0);
        }

#pragma unroll
    for (int mt = 0; mt < 2; ++mt) {
#pragma unroll
        for (int r = 0; r < 4; ++r) {
            int sp = m0 + mt * 16 + quad * 4 + r;
            if (sp >= 841) continue;
#pragma unroll
            for (int nt = 0; nt < 2; ++nt) {
                int co = (wv * 2 + nt) * 16 + mr;
                float y = acc[mt][nt][r] + bias[co];
                out[((size_t)b * 841 + sp) * 128 + co] = (_Float16)fmaxf(y, 0.f);
            }
        }
    }
}

// ---------------------------------------------------------------------------
// conv2/conv3 implicit-GEMM MFMA, NHWC in/out — r22: KSPL=1 fused epilogue
// + MTILE 32: conv2 16x28=448 blocks, conv3 16x48=768. (verified r22/r24)
// ---------------------------------------------------------------------------
template<int CIN, int COUT, int Kk, int S, int IN, int OUT,
         int NPB, int KCH, int MTILE>
__global__ __launch_bounds__(256) void conv_fused_mfma(
    const _Float16* __restrict__ in_h,
    const _Float16* __restrict__ w_h,
    const float* __restrict__ bias,
    _Float16* __restrict__ out)          // [B][OSZ][COUT] NHWC f16
{
    constexpr int KK   = Kk * Kk;
    constexpr int OSZ  = OUT * OUT;
    constexpr int MP   = MTILE;
    constexpr int MT   = MTILE / 16;
    constexpr int KTOT = CIN * KK;
    constexpr int NCHUNK = KTOT / KCH;
    constexpr int NSPL = COUT / NPB;
    constexpr int KSN  = KCH / 32;
    constexpr int SLOTS = MP * (KCH / 8);

    const int b    = blockIdx.x;
    const int m0   = (blockIdx.y / NSPL) * MTILE;
    const int co0  = (blockIdx.y % NSPL) * NPB;
    const int tid  = threadIdx.x;
    const int wv   = tid >> 6;
    const int lane = tid & 63;
    const int quad = lane >> 4;
    const int mr   = lane & 15;

    __shared__ __align__(16) _Float16 A_lds[MP * KCH];

    const _Float16* inb = in_h + (size_t)b * (IN * IN) * CIN;

    f32x4 acc[MT];
#pragma unroll
    for (int mt = 0; mt < MT; ++mt) acc[mt] = (f32x4){0.f, 0.f, 0.f, 0.f};

    for (int ch = 0; ch < NCHUNK; ++ch) {
        const int k0 = ch * KCH;
        __syncthreads();
        for (int slot = tid; slot < SLOTS; slot += 256) {
            int m  = slot % MP;
            int kg = slot / MP;
            int mg = m0 + m;
            bool mok = (mg < OSZ);
            int oh = mok ? mg / OUT : 0;
            int ow = mok ? mg % OUT : 0;
            int kbase = k0 + kg * 8;
            int khkw = kbase / CIN;
            int ci0  = kbase % CIN;
            int kh = khkw / Kk, kw = khkw % Kk;
            f16x8 av = (f16x8)(_Float16)0.f;
            if (mok)
                av = *(const f16x8*)&inb[((size_t)((oh * S + kh) * IN + (ow * S + kw))) * CIN + ci0];
            *(f16x8*)&A_lds[(kg * MP + m) * 8] = av;
        }
        __syncthreads();
        f16x8 wf[KSN];
        const int co = co0 + wv * 16 + mr;
#pragma unroll
        for (int ks = 0; ks < KSN; ++ks)
            wf[ks] = *(const f16x8*)&w_h[(size_t)co * KTOT + k0 + ks * 32 + quad * 8];
#pragma unroll
        for (int ks = 0; ks < KSN; ++ks) {
#pragma unroll
            for (int mt = 0; mt < MT; ++mt) {
                f16x8 bv = *(const f16x8*)&A_lds[((ks * 4 + quad) * MP + mt * 16 + mr) * 8];
                acc[mt] = __builtin_amdgcn_mfma_f32_16x16x32_f16(bv, wf[ks], acc[mt], 0, 0, 0);
            }
        }
    }

    const int co = co0 + wv * 16 + mr;
    const float bb = bias[co];
#pragma unroll
    for (int mt = 0; mt < MT; ++mt) {
#pragma unroll
        for (int r = 0; r < 4; ++r) {
            int sp = m0 + mt * 16 + quad * 4 + r;
            if (sp >= OSZ) continue;
            float y = acc[mt][r] + bb;
            out[((size_t)b * OSZ + sp) * COUT + co] = (_Float16)fmaxf(y, 0.f);
        }
    }
}

// ---------------------------------------------------------------------------
// fc as split-K MFMA — r28: K-split 169 -> 338 blocks (256 K-elems/block,
// 2 MFMA/wave) for TLP (0.66 -> 1.3 blocks/CU). Atomic accumulation order
// changes (f32 ulp jitter only).
// ---------------------------------------------------------------------------
__global__ __launch_bounds__(256) void fc_mfma(
    const _Float16* __restrict__ z, const _Float16* __restrict__ fcw,
    float* __restrict__ out, int NO)
{
    const int tid  = threadIdx.x;
    const int wv   = tid >> 6;
    const int lane = tid & 63;
    const int quad = lane >> 4;
    const int mr   = lane & 15;
    const int kw0  = blockIdx.x * 256 + wv * 64;

    __shared__ float sred[1024];

    f32x4 acc = (f32x4){0.f, 0.f, 0.f, 0.f};
    const bool bok = (mr < NO);
#pragma unroll
    for (int ks = 0; ks < 2; ++ks) {
        int kk = kw0 + ks * 32 + quad * 8;
        f16x8 av = *(const f16x8*)&z[(size_t)mr * 86528 + kk];
        f16x8 bw = (f16x8)(_Float16)0.f;
        if (bok) bw = *(const f16x8*)&fcw[(size_t)mr * 86528 + kk];
        acc = __builtin_amdgcn_mfma_f32_16x16x32_f16(av, bw, acc, 0, 0, 0);
    }
#pragma unroll
    for (int r = 0; r < 4; ++r)
        sred[wv * 256 + (quad * 4 + r) * 16 + mr] = acc[r];
    __syncthreads();
    if (tid < 256) {
        float s = sred[tid] + sred[256 + tid] + sred[512 + tid] + sred[768 + tid];
        int o = tid & 15, b = tid >> 4;
        if (o < NO) atomicAdd(&out[b * NO + o], s);
    }
}

// ---------------------------------------------------------------------------
// ONE weight-prep kernel (r15, verified).
// ---------------------------------------------------------------------------
__global__ __launch_bounds__(256) void prep_weights(
    const float* __restrict__ w1s, const float* __restrict__ w1i,
    const float* __restrict__ w2s, const float* __restrict__ w3s,
    const float* __restrict__ w2i, const float* __restrict__ w3i,
    const float* __restrict__ fcs, const float* __restrict__ fci,
    _Float16* __restrict__ w1h, _Float16* __restrict__ w23,
    _Float16* __restrict__ fch, float* __restrict__ zp)
{
    const int R0 = 384;
    const int R1 = 24576;
    const int N2 = 294912, N3 = 524288;
    const int R2 = 2 * (N2 + N3);
    const int K = 86528;
    const int R3 = 12 * K;
    const int T = R0 + R1 + R2 + R3;
    for (int i = blockIdx.x * 256 + threadIdx.x; i < T; i += gridDim.x * 256) {
        if (i < R0) {
            zp[i] = 0.f;
        } else if (i < R0 + R1) {
            int r0 = i - R0;
            int br = r0 / 12288, r = r0 % 12288;
            int co = r / 96, k = r % 96;
            const float* s = br ? w1i : w1s;
            w1h[r0] = (k < 75) ? (_Float16)s[co * 75 + k] : (_Float16)0.f;
        } else if (i < R0 + R1 + R2) {
            int j = i - R0 - R1;
            int out_idx = j;
            const float* s; int CK, KKn;
            if (j < N2)                { s = w2s; CK = 1152; KKn = 9; }
            else if (j < N2 + N3)      { s = w3s; j -= N2; CK = 1024; KKn = 4; }
            else if (j < 2 * N2 + N3)  { s = w2i; j -= N2 + N3; CK = 1152; KKn = 9; }
            else                       { s = w3i; j -= 2 * N2 + N3; CK = 1024; KKn = 4; }
            int co = j / CK, rem = j % CK;
            int ci = rem % (CK / KKn), khkw = rem / (CK / KKn);
            w23[out_idx] = (_Float16)s[co * CK + ci * KKn + khkw];
        } else {
            int j = i - R0 - R1 - R2;
            int o = j / K, rem = j % K;
            int sp = rem / 512, co = rem % 512;
            const float* s = (o < 9) ? (fcs + o * K) : (fci + (o - 9) * K);
            fch[j] = (_Float16)s[co * 169 + sp];
        }
    }
}

// ---------------------------------------------------------------------------
// m = reshape(|h|,3,3)^T; n = max L1 row norm + 1e-4; msc = m / n.
// ---------------------------------------------------------------------------
__global__ void build_m(const float* __restrict__ h, float* __restrict__ msc)
{
    int b = threadIdx.x;
    if (b < 16) {
        float m[9];
#pragma unroll
        for (int i = 0; i < 3; ++i)
#pragma unroll
            for (int j = 0; j < 3; ++j) m[i * 3 + j] = fabsf(h[b * 9 + j * 3 + i]);
        float n = 0.f;
#pragma unroll
        for (int i = 0; i < 3; ++i) {
            float r = m[i * 3] + m[i * 3 + 1] + m[i * 3 + 2];
            n = fmaxf(n, r);
        }
        n += 1e-4f;
        float inv = 1.f / n;
#pragma unroll
        for (int k = 0; k < 9; ++k) msc[b * 9 + k] = m[k] * inv;
    }
}

// ---------------------------------------------------------------------------
// est[b] = inv(msc[b]) @ |ill[b]|
// ---------------------------------------------------------------------------
__global__ void final_est(const float* __restrict__ msc, const float* __restrict__ ill,
                          float* __restrict__ out)
{
    int bidx = threadIdx.x;
    if (bidx < 16) {
        const float* m = msc + bidx * 9;
        float a = m[0], b = m[1], c = m[2];
        float d = m[3], e = m[4], f = m[5];
        float g = m[6], h = m[7], i = m[8];
        float A = e * i - f * h, B = f * g - d * i, C = d * h - e * g;
        float D = c * h - b * i, E = a * i - c * g, F = b * g - a * h;
        float G = b * f - c * e, H = c * d - a * f, I = a * e - b * d;
        float det = a * A + b * B + c * C;
        float inv_det = 1.f / det;
        float x0 = fabsf(ill[bidx * 3 + 0]);
        float x1 = fabsf(ill[bidx * 3 + 1]);
        float x2 = fabsf(ill[bidx * 3 + 2]);
        out[bidx * 3 + 0] = (A * x0 + D * x1 + G * x2) * inv_det;
        out[bidx * 3 + 1] = (B * x0 + E * x1 + H * x2) * inv_det;
        out[bidx * 3 + 2] = (C * x0 + F * x1 + I * x2) * inv_det;
    }
}

extern "C" void kernel_launch(void* const* d_in, const int* in_sizes, int n_in,
                              void* d_out, int out_size, void* d_ws, size_t ws_size,
                              hipStream_t stream)
{
    (void)in_sizes; (void)n_in; (void)out_size; (void)ws_size;
    const float* image = (const float*)d_in[0];
    const float* su_s  = (const float*)d_in[1];
    const float* sv_s  = (const float*)d_in[2];
    const float* c_s   = (const float*)d_in[3];
    const float* w1_s  = (const float*)d_in[4];
    const float* b1_s  = (const float*)d_in[5];
    const float* w2_s  = (const float*)d_in[6];
    const float* b2_s  = (const float*)d_in[7];
    const float* w3_s  = (const float*)d_in[8];
    const float* b3_s  = (const float*)d_in[9];
    const float* fc_s  = (const float*)d_in[10];
    const float* su_i  = (const float*)d_in[11];
    const float* sv_i  = (const float*)d_in[12];
    const float* c_i   = (const float*)d_in[13];
    const float* w1_i  = (const float*)d_in[14];
    const float* b1_i  = (const float*)d_in[15];
    const float* w2_i  = (const float*)d_in[16];
    const float* b2_i  = (const float*)d_in[17];
    const float* w3_i  = (const float*)d_in[18];
    const float* b3_i  = (const float*)d_in[19];
    const float* fc_i  = (const float*)d_in[20];

    // ---- workspace: cumulative pointer arithmetic ONLY (r22 layout;
    //      hpart 48*45*4096 = 8,847,360 f < 11,075,584 reserved)
    float* W      = (float*)d_ws;
    float* hist   = W;                        // 178608 f
    float* hd     = hist + 178608;            // 144 (zeroed in prep)
    float* hd2    = hd + 144;                 // 144
    float* hsum3a = hd2 + 144;                // 48
    float* hsum3b = hsum3a + 48;              // 48
    float* msc    = hsum3b + 48;              // 144
    float* U      = msc + 144;
    float* hpart  = U;
    _Float16* o1h   = (_Float16*)(U + 11075584);
    _Float16* o2h   = o1h   + 1722368;
    _Float16* o3h   = o2h   + 802816;
    _Float16* fch   = o3h   + 1384448;
    _Float16* w2h_s = fch   + 1038336;
    _Float16* w3h_s = w2h_s + 294912;
    _Float16* w2h_i = w3h_s + 524288;
    _Float16* w3h_i = w2h_i + 294912;
    _Float16* w1h_s = w3h_i + 524288;
    _Float16* w1h_i = w1h_s + 12288;

    const int FCK = 86528;

    prep_weights<<<1024, 256, 0, stream>>>(w1_s, w1_i, w2_s, w3_s, w2_i, w3_i,
                                           fc_s, fc_i, w1h_s, w2h_s, fch, hd);

    // ================= sensor branch =================
    hist_mfma<<<dim3(48, HSP), 256, 0, stream>>>(image, su_s, sv_s, c_s, nullptr, hpart);
    reduce_hist<<<dim3(48, 16), 256, 0, stream>>>(hpart, hist, hsum3a);
    conv1_mfma<<<dim3(16, 27), 256, 0, stream>>>(hist, hsum3a, w1h_s, b1_s, o1h);
    conv_fused_mfma<128, 256, 3, 2, 29, 14, 64, 96, 32><<<dim3(16, 28), 256, 0, stream>>>(o1h, w2h_s, b2_s, o2h);
    conv_fused_mfma<256, 512, 2, 1, 14, 13, 64, 64, 32><<<dim3(16, 48), 256, 0, stream>>>(o2h, w3h_s, b3_s, o3h);
    fc_mfma<<<338, 256, 0, stream>>>(o3h, fch, hd, 9);
    build_m<<<1, 64, 0, stream>>>(hd, msc);

    // ================= illuminant branch =================
    hist_mfma<<<dim3(48, HSP), 256, 0, stream>>>(image, su_i, sv_i, c_i, msc, hpart);
    reduce_hist<<<dim3(48, 16), 256, 0, stream>>>(hpart, hist, hsum3b);
    conv1_mfma<<<dim3(16, 27), 256, 0, stream>>>(hist, hsum3b, w1h_i, b1_i, o1h);
    conv_fused_mfma<128, 256, 3, 2, 29, 14, 64, 96, 32><<<dim3(16, 28), 256, 0, stream>>>(o1h, w2h_i, b2_i, o2h);
    conv_fused_mfma<256, 512, 2, 1, 14, 13, 64, 64, 32><<<dim3(16, 48), 256, 0, stream>>>(o2h, w3h_i, b3_i, o3h);
    fc_mfma<<<338, 256, 0, stream>>>(o3h, fch + 9 * FCK, hd2, 3);
    final_est<<<1, 64, 0, stream>>>(msc, hd2, (float*)d_out);
}

// Round 17
// 305.033 us; speedup vs baseline: 1.0508x; 1.0508x over previous
//
#include <hip/hip_runtime.h>

#define P_PIX 22500
#define HB 61
#define HSP 45
#define PPB 512
#define NCHK 4

typedef float f32x4 __attribute__((ext_vector_type(4)));
typedef _Float16 f16x8 __attribute__((ext_vector_type(8)));
typedef _Float16 f16x4 __attribute__((ext_vector_type(4)));

// one-instruction f32 pair -> packed f16x2 (RTZ), as raw u32
static __device__ __forceinline__ unsigned pk2(float a, float b)
{
    return __builtin_bit_cast(unsigned, __builtin_amdgcn_cvt_pkrtz(a, b));
}

// raw v_exp_f32: computes 2^x (ISA: D=2^S0)
static __device__ __forceinline__ float exp2_hw(float x)
{
    return __builtin_amdgcn_exp2f(x);
}

// ---------------------------------------------------------------------------
// MFMA RGB-uv soft histogram (r22, verified — part of 305.2us session best).
// Ladder: exp2 folded constant + cvt_pkrtz packs (r19), weight folded into
// exponent + B_lds dbuf 1-barrier/chunk (r21), HSP=45 TLP (r22).
// REJECTED by measurement: atomic epilogue (r23: +62us), single-buffer LDS
// + wide conv K-chunks (r25: noise), last-block tail fusion (r26: +10us),
// fc K-split x2 + reduce x2 (r28: +15us, atomic contention).
// ---------------------------------------------------------------------------
__global__ __launch_bounds__(256) void hist_mfma(
    const float* __restrict__ img, const float* __restrict__ su,
    const float* __restrict__ sv, const float* __restrict__ cw,
    const float* __restrict__ msc, float* __restrict__ hpart)
{
    const int bc = blockIdx.x;
    const int b = bc / 3, c = bc % 3;
    const int split = blockIdx.y;
    const int tid  = threadIdx.x;
    const int wv   = tid >> 6;
    const int lane = tid & 63;
    const int quad = lane >> 4;
    const int mr   = lane & 15;

    __shared__ __align__(16) _Float16 B_lds[2][8192]; // 2 x 16 KB, dbuf
    __shared__ __align__(16) float su_l[PPB];         // staged log-chroma u
    __shared__ __align__(16) float sv_l[PPB];         // staged log-chroma v
    __shared__ __align__(16) float lw_l[PPB];         // staged log2(Iy*c)

    const float sig_u = su[c], sig_v = sv[c];
    const float L2E = 1.4426950408889634f;
    const float c1u = -L2E / (sig_u * sig_u);
    const float c1v = -L2E / (sig_v * sig_v);
    const float cwc = cw[c];
    const float ubin_b = -3.f + 0.1f * (float)lane;
    const float ubin_a = -3.f + 0.1f * (float)(wv * 16 + mr);

    const bool hasM = (msc != nullptr);
    float m00=0,m01=0,m02=0,m10=0,m11=0,m12=0,m20=0,m21=0,m22=0;
    if (hasM) {
        const float* mp = msc + b * 9;
        m00=mp[0]; m01=mp[1]; m02=mp[2];
        m10=mp[3]; m11=mp[4]; m12=mp[5];
        m20=mp[6]; m21=mp[7]; m22=mp[8];
    }

    const int p0 = split * PPB;

    // ---- phase 0: stage all PPB pixels (coalesced, all 256 threads) ----
    for (int i = tid; i < PPB; i += 256) {
        int px = p0 + i;
        float u = 0.f, v = 0.f, wgt = 0.f;
        if (px < P_PIX) {
            const float* ip = img + (size_t)b * 3 * P_PIX + px;
            float r = ip[0], g = ip[P_PIX], bl = ip[2 * P_PIX];
            if (hasM) {
                float r2 = m00 * r + m01 * g + m02 * bl;
                float g2 = m10 * r + m11 * g + m12 * bl;
                float b2 = m20 * r + m21 * g + m22 * bl;
                r = r2; g = g2; bl = b2;
            }
            r  = fminf(fmaxf(r, 0.f), 1.f);
            g  = fminf(fmaxf(g, 0.f), 1.f);
            bl = fminf(fmaxf(bl, 0.f), 1.f);
            float Iy = sqrtf(r * r + g * g + bl * bl);
            float lr = __logf(r + 1e-6f);
            float lg = __logf(g + 1e-6f);
            float lb = __logf(bl + 1e-6f);
            if (c == 0)      { u = lr - lg; v = lr - lb; }
            else if (c == 1) { u = lg - lr; v = lg - lb; }
            else             { u = lb - lr; v = lb - lg; }
            wgt = Iy * cwc;
        }
        su_l[i] = u; sv_l[i] = v;
        lw_l[i] = __log2f(wgt);   // wgt=0 (incl. px out of range) -> -inf -> exp2 = 0
    }
    __syncthreads();

    f32x4 acc[4];
#pragma unroll
    for (int nt = 0; nt < 4; ++nt) acc[nt] = (f32x4){0.f, 0.f, 0.f, 0.f};

    for (int chunk = 0; chunk < NCHK; ++chunk) {
        const float* suc = &su_l[chunk * 128];
        const float* svc = &sv_l[chunk * 128];
        const float* lwc = &lw_l[chunk * 128];
        _Float16* Bbuf = &B_lds[chunk & 1][0];

        // B tile: v-kernel exps -> LDS (f16), double-buffered
#pragma unroll
        for (int r = 0; r < 4; ++r) {
            int pg = wv + 4 * r;
            f32x4 v0 = *(const f32x4*)&svc[pg * 8];
            f32x4 v1 = *(const f32x4*)&svc[pg * 8 + 4];
            float e[8];
#pragma unroll
            for (int j = 0; j < 4; ++j) {
                float d0 = v0[j] - ubin_b;
                e[j] = exp2_hw((d0 * c1v) * d0);
                float d1 = v1[j] - ubin_b;
                e[4 + j] = exp2_hw((d1 * c1v) * d1);
            }
            union { f16x8 h; unsigned w[4]; } bv;
            bv.w[0] = pk2(e[0], e[1]);
            bv.w[1] = pk2(e[2], e[3]);
            bv.w[2] = pk2(e[4], e[5]);
            bv.w[3] = pk2(e[6], e[7]);
            *(f16x8*)&Bbuf[(pg * 64 + lane) * 8] = bv.h;
        }
        // A fragments: u-kernel exps with weight folded into exponent
        f16x8 af[4];
#pragma unroll
        for (int kk = 0; kk < 4; ++kk) {
            int pxg = kk * 4 + quad;
            f32x4 u0 = *(const f32x4*)&suc[pxg * 8];
            f32x4 u1 = *(const f32x4*)&suc[pxg * 8 + 4];
            f32x4 l0 = *(const f32x4*)&lwc[pxg * 8];
            f32x4 l1 = *(const f32x4*)&lwc[pxg * 8 + 4];
            float e[8];
#pragma unroll
            for (int j = 0; j < 4; ++j) {
                float d0 = u0[j] - ubin_a;
                e[j] = exp2_hw(__builtin_fmaf(d0 * c1u, d0, l0[j]));
                float d1 = u1[j] - ubin_a;
                e[4 + j] = exp2_hw(__builtin_fmaf(d1 * c1u, d1, l1[j]));
            }
            union { f16x8 h; unsigned w[4]; } av;
            av.w[0] = pk2(e[0], e[1]);
            av.w[1] = pk2(e[2], e[3]);
            av.w[2] = pk2(e[4], e[5]);
            av.w[3] = pk2(e[6], e[7]);
            af[kk] = av.h;
        }
        __syncthreads();
#pragma unroll
        for (int kk = 0; kk < 4; ++kk) {
            int pgq = kk * 4 + quad;
#pragma unroll
            for (int nt = 0; nt < 4; ++nt) {
                f16x8 bvv = *(const f16x8*)&Bbuf[(pgq * 64 + nt * 16 + mr) * 8];
                acc[nt] = __builtin_amdgcn_mfma_f32_16x16x32_f16(af[kk], bvv, acc[nt], 0, 0, 0);
            }
        }
        // no trailing barrier: dbuf — buffer k rewritten only at k+2, which
        // is separated from MFMA(k) by barrier(k+1).
    }

    float* hp = hpart + ((size_t)bc * HSP + split) * 4096;
#pragma unroll
    for (int nt = 0; nt < 4; ++nt) {
        int v = nt * 16 + mr;
#pragma unroll
        for (int r = 0; r < 4; ++r) {
            int u = wv * 16 + quad * 4 + r;
            hp[u * 64 + v] = acc[nt][r];
        }
    }
}

// ---------------------------------------------------------------------------
// Sum HSP slabs -> hist; per-(b,c) total -> hsum3 (r24, grid (48,8)).
// ---------------------------------------------------------------------------
__global__ __launch_bounds__(256) void reduce_hist(
    const float* __restrict__ hpart, float* __restrict__ hist,
    float* __restrict__ hsum3)
{
    const int bc = blockIdx.x;
    const int part = blockIdx.y;
    const int tid = threadIdx.x;
    const float* base = hpart + (size_t)bc * HSP * 4096;
    float lsum = 0.f;
#pragma unroll
    for (int t = 0; t < 2; ++t) {
        int idx = part * 512 + t * 256 + tid;
        int u = idx >> 6, v = idx & 63;
        float s = 0.f;
        for (int sp = 0; sp < HSP; ++sp) s += base[sp * 4096 + idx];
        if (u < HB && v < HB) {
            hist[(size_t)bc * (HB * HB) + u * HB + v] = s;
            lsum += s;
        }
    }
    __shared__ float red[4];
    for (int off = 32; off; off >>= 1) lsum += __shfl_down(lsum, off, 64);
    if ((tid & 63) == 0) red[tid >> 6] = lsum;
    __syncthreads();
    if (tid == 0) atomicAdd(&hsum3[bc], red[0] + red[1] + red[2] + red[3]);
}

// ---------------------------------------------------------------------------
// conv1 implicit-GEMM MFMA, NHWC output — r27: M-tile 32, grid (16,27)=432
// blocks. (verified −3.2us in r27)
// ---------------------------------------------------------------------------
__global__ __launch_bounds__(256) void conv1_mfma(
    const float* __restrict__ hist, const float* __restrict__ hsum3,
    const _Float16* __restrict__ w1h, const float* __restrict__ bias,
    _Float16* __restrict__ out)
{
    const int b    = blockIdx.x;
    const int m0   = blockIdx.y * 32;
    const int tid  = threadIdx.x;
    const int wv   = tid >> 6;
    const int lane = tid & 63;
    const int quad = lane >> 4;
    const int mr   = lane & 15;

    __shared__ __align__(16) _Float16 A_lds[32 * 96];

    const float sc = 1.f / (hsum3[b * 3] + hsum3[b * 3 + 1] + hsum3[b * 3 + 2] + 1e-6f);
    const float* inb = hist + (size_t)b * 3 * 3721;

    for (int slot = tid; slot < 384; slot += 256) {
        int m  = slot & 31;
        int kg = slot >> 5;
        int mg = m0 + m;
        bool mok = (mg < 841);
        int oh = mok ? mg / 29 : 0;
        int ow = mok ? mg % 29 : 0;
        const float* pbase = inb + (oh * 2) * 61 + (ow * 2);
        f16x8 av;
#pragma unroll
        for (int j = 0; j < 8; ++j) {
            int k = kg * 8 + j;
            float x = 0.f;
            if (mok && k < 75) {
                int ci = k / 25, r = k % 25;
                int kh = r / 5, kw = r % 5;
                x = pbase[ci * 3721 + kh * 61 + kw] * sc;
            }
            av[j] = (_Float16)x;
        }
        *(f16x8*)&A_lds[(kg * 32 + m) * 8] = av;
    }
    __syncthreads();

    f16x8 wf[3][2];
#pragma unroll
    for (int ks = 0; ks < 3; ++ks)
#pragma unroll
        for (int nt = 0; nt < 2; ++nt) {
            int co = (wv * 2 + nt) * 16 + mr;
            wf[ks][nt] = *(const f16x8*)&w1h[co * 96 + ks * 32 + quad * 8];
        }

    f32x4 acc[2][2];
#pragma unroll
    for (int mt = 0; mt < 2; ++mt)
#pragma unroll
        for (int nt = 0; nt < 2; ++nt) acc[mt][nt] = (f32x4){0.f, 0.f, 0.f, 0.f};

#pragma unroll
    for (int ks = 0; ks < 3; ++ks)
#pragma unroll
        for (int mt = 0; mt < 2; ++mt) {
            f16x8 bv = *(const f16x8*)&A_lds[((ks * 4 + quad) * 32 + mt * 16 + mr) * 8];
#pragma unroll
            for (int nt = 0; nt < 2; ++nt)
                acc[mt][nt] = __builtin_amdgcn_mfma_f32_16x16x32_f16(bv, wf[ks][nt], acc[mt][nt], 0, 0, 0);
        }

#pragma unroll
    for (int mt = 0; mt < 2; ++mt) {
#pragma unroll
        for (int r = 0; r < 4; ++r) {
            int sp = m0 + mt * 16 + quad * 4 + r;
            if (sp >= 841) continue;
#pragma unroll
            for (int nt = 0; nt < 2; ++nt) {
                int co = (wv * 2 + nt) * 16 + mr;
                float y = acc[mt][nt][r] + bias[co];
                out[((size_t)b * 841 + sp) * 128 + co] = (_Float16)fmaxf(y, 0.f);
            }
        }
    }
}

// ---------------------------------------------------------------------------
// conv2/conv3 implicit-GEMM MFMA, NHWC in/out — r22: KSPL=1 fused epilogue
// + MTILE 32: conv2 16x28=448 blocks, conv3 16x48=768. (verified r22/r24)
// ---------------------------------------------------------------------------
template<int CIN, int COUT, int Kk, int S, int IN, int OUT,
         int NPB, int KCH, int MTILE>
__global__ __launch_bounds__(256) void conv_fused_mfma(
    const _Float16* __restrict__ in_h,
    const _Float16* __restrict__ w_h,
    const float* __restrict__ bias,
    _Float16* __restrict__ out)          // [B][OSZ][COUT] NHWC f16
{
    constexpr int KK   = Kk * Kk;
    constexpr int OSZ  = OUT * OUT;
    constexpr int MP   = MTILE;
    constexpr int MT   = MTILE / 16;
    constexpr int KTOT = CIN * KK;
    constexpr int NCHUNK = KTOT / KCH;
    constexpr int NSPL = COUT / NPB;
    constexpr int KSN  = KCH / 32;
    constexpr int SLOTS = MP * (KCH / 8);

    const int b    = blockIdx.x;
    const int m0   = (blockIdx.y / NSPL) * MTILE;
    const int co0  = (blockIdx.y % NSPL) * NPB;
    const int tid  = threadIdx.x;
    const int wv   = tid >> 6;
    const int lane = tid & 63;
    const int quad = lane >> 4;
    const int mr   = lane & 15;

    __shared__ __align__(16) _Float16 A_lds[MP * KCH];

    const _Float16* inb = in_h + (size_t)b * (IN * IN) * CIN;

    f32x4 acc[MT];
#pragma unroll
    for (int mt = 0; mt < MT; ++mt) acc[mt] = (f32x4){0.f, 0.f, 0.f, 0.f};

    for (int ch = 0; ch < NCHUNK; ++ch) {
        const int k0 = ch * KCH;
        __syncthreads();
        for (int slot = tid; slot < SLOTS; slot += 256) {
            int m  = slot % MP;
            int kg = slot / MP;
            int mg = m0 + m;
            bool mok = (mg < OSZ);
            int oh = mok ? mg / OUT : 0;
            int ow = mok ? mg % OUT : 0;
            int kbase = k0 + kg * 8;
            int khkw = kbase / CIN;
            int ci0  = kbase % CIN;
            int kh = khkw / Kk, kw = khkw % Kk;
            f16x8 av = (f16x8)(_Float16)0.f;
            if (mok)
                av = *(const f16x8*)&inb[((size_t)((oh * S + kh) * IN + (ow * S + kw))) * CIN + ci0];
            *(f16x8*)&A_lds[(kg * MP + m) * 8] = av;
        }
        __syncthreads();
        f16x8 wf[KSN];
        const int co = co0 + wv * 16 + mr;
#pragma unroll
        for (int ks = 0; ks < KSN; ++ks)
            wf[ks] = *(const f16x8*)&w_h[(size_t)co * KTOT + k0 + ks * 32 + quad * 8];
#pragma unroll
        for (int ks = 0; ks < KSN; ++ks) {
#pragma unroll
            for (int mt = 0; mt < MT; ++mt) {
                f16x8 bv = *(const f16x8*)&A_lds[((ks * 4 + quad) * MP + mt * 16 + mr) * 8];
                acc[mt] = __builtin_amdgcn_mfma_f32_16x16x32_f16(bv, wf[ks], acc[mt], 0, 0, 0);
            }
        }
    }

    const int co = co0 + wv * 16 + mr;
    const float bb = bias[co];
#pragma unroll
    for (int mt = 0; mt < MT; ++mt) {
#pragma unroll
        for (int r = 0; r < 4; ++r) {
            int sp = m0 + mt * 16 + quad * 4 + r;
            if (sp >= OSZ) continue;
            float y = acc[mt][r] + bb;
            out[((size_t)b * OSZ + sp) * COUT + co] = (_Float16)fmaxf(y, 0.f);
        }
    }
}

// ---------------------------------------------------------------------------
// fc as split-K MFMA (r14, verified; r28's K-split x2 REJECTED: atomic
// contention on hd/hd2 outweighed the TLP gain, +15us).
// ---------------------------------------------------------------------------
__global__ __launch_bounds__(256) void fc_mfma(
    const _Float16* __restrict__ z, const _Float16* __restrict__ fcw,
    float* __restrict__ out, int NO)
{
    const int tid  = threadIdx.x;
    const int wv   = tid >> 6;
    const int lane = tid & 63;
    const int quad = lane >> 4;
    const int mr   = lane & 15;
    const int kw0  = blockIdx.x * 512 + wv * 128;

    __shared__ float sred[1024];

    f32x4 acc = (f32x4){0.f, 0.f, 0.f, 0.f};
    const bool bok = (mr < NO);
#pragma unroll
    for (int ks = 0; ks < 4; ++ks) {
        int kk = kw0 + ks * 32 + quad * 8;
        f16x8 av = *(const f16x8*)&z[(size_t)mr * 86528 + kk];
        f16x8 bw = (f16x8)(_Float16)0.f;
        if (bok) bw = *(const f16x8*)&fcw[(size_t)mr * 86528 + kk];
        acc = __builtin_amdgcn_mfma_f32_16x16x32_f16(av, bw, acc, 0, 0, 0);
    }
#pragma unroll
    for (int r = 0; r < 4; ++r)
        sred[wv * 256 + (quad * 4 + r) * 16 + mr] = acc[r];
    __syncthreads();
    if (tid < 256) {
        float s = sred[tid] + sred[256 + tid] + sred[512 + tid] + sred[768 + tid];
        int o = tid & 15, b = tid >> 4;
        if (o < NO) atomicAdd(&out[b * NO + o], s);
    }
}

// ---------------------------------------------------------------------------
// ONE weight-prep kernel (r15, verified).
// ---------------------------------------------------------------------------
__global__ __launch_bounds__(256) void prep_weights(
    const float* __restrict__ w1s, const float* __restrict__ w1i,
    const float* __restrict__ w2s, const float* __restrict__ w3s,
    const float* __restrict__ w2i, const float* __restrict__ w3i,
    const float* __restrict__ fcs, const float* __restrict__ fci,
    _Float16* __restrict__ w1h, _Float16* __restrict__ w23,
    _Float16* __restrict__ fch, float* __restrict__ zp)
{
    const int R0 = 384;
    const int R1 = 24576;
    const int N2 = 294912, N3 = 524288;
    const int R2 = 2 * (N2 + N3);
    const int K = 86528;
    const int R3 = 12 * K;
    const int T = R0 + R1 + R2 + R3;
    for (int i = blockIdx.x * 256 + threadIdx.x; i < T; i += gridDim.x * 256) {
        if (i < R0) {
            zp[i] = 0.f;
        } else if (i < R0 + R1) {
            int r0 = i - R0;
            int br = r0 / 12288, r = r0 % 12288;
            int co = r / 96, k = r % 96;
            const float* s = br ? w1i : w1s;
            w1h[r0] = (k < 75) ? (_Float16)s[co * 75 + k] : (_Float16)0.f;
        } else if (i < R0 + R1 + R2) {
            int j = i - R0 - R1;
            int out_idx = j;
            const float* s; int CK, KKn;
            if (j < N2)                { s = w2s; CK = 1152; KKn = 9; }
            else if (j < N2 + N3)      { s = w3s; j -= N2; CK = 1024; KKn = 4; }
            else if (j < 2 * N2 + N3)  { s = w2i; j -= N2 + N3; CK = 1152; KKn = 9; }
            else                       { s = w3i; j -= 2 * N2 + N3; CK = 1024; KKn = 4; }
            int co = j / CK, rem = j % CK;
            int ci = rem % (CK / KKn), khkw = rem / (CK / KKn);
            w23[out_idx] = (_Float16)s[co * CK + ci * KKn + khkw];
        } else {
            int j = i - R0 - R1 - R2;
            int o = j / K, rem = j % K;
            int sp = rem / 512, co = rem % 512;
            const float* s = (o < 9) ? (fcs + o * K) : (fci + (o - 9) * K);
            fch[j] = (_Float16)s[co * 169 + sp];
        }
    }
}

// ---------------------------------------------------------------------------
// m = reshape(|h|,3,3)^T; n = max L1 row norm + 1e-4; msc = m / n.
// ---------------------------------------------------------------------------
__global__ void build_m(const float* __restrict__ h, float* __restrict__ msc)
{
    int b = threadIdx.x;
    if (b < 16) {
        float m[9];
#pragma unroll
        for (int i = 0; i < 3; ++i)
#pragma unroll
            for (int j = 0; j < 3; ++j) m[i * 3 + j] = fabsf(h[b * 9 + j * 3 + i]);
        float n = 0.f;
#pragma unroll
        for (int i = 0; i < 3; ++i) {
            float r = m[i * 3] + m[i * 3 + 1] + m[i * 3 + 2];
            n = fmaxf(n, r);
        }
        n += 1e-4f;
        float inv = 1.f / n;
#pragma unroll
        for (int k = 0; k < 9; ++k) msc[b * 9 + k] = m[k] * inv;
    }
}

// ---------------------------------------------------------------------------
// est[b] = inv(msc[b]) @ |ill[b]|
// ---------------------------------------------------------------------------
__global__ void final_est(const float* __restrict__ msc, const float* __restrict__ ill,
                          float* __restrict__ out)
{
    int bidx = threadIdx.x;
    if (bidx < 16) {
        const float* m = msc + bidx * 9;
        float a = m[0], b = m[1], c = m[2];
        float d = m[3], e = m[4], f = m[5];
        float g = m[6], h = m[7], i = m[8];
        float A = e * i - f * h, B = f * g - d * i, C = d * h - e * g;
        float D = c * h - b * i, E = a * i - c * g, F = b * g - a * h;
        float G = b * f - c * e, H = c * d - a * f, I = a * e - b * d;
        float det = a * A + b * B + c * C;
        float inv_det = 1.f / det;
        float x0 = fabsf(ill[bidx * 3 + 0]);
        float x1 = fabsf(ill[bidx * 3 + 1]);
        float x2 = fabsf(ill[bidx * 3 + 2]);
        out[bidx * 3 + 0] = (A * x0 + D * x1 + G * x2) * inv_det;
        out[bidx * 3 + 1] = (B * x0 + E * x1 + H * x2) * inv_det;
        out[bidx * 3 + 2] = (C * x0 + F * x1 + I * x2) * inv_det;
    }
}

extern "C" void kernel_launch(void* const* d_in, const int* in_sizes, int n_in,
                              void* d_out, int out_size, void* d_ws, size_t ws_size,
                              hipStream_t stream)
{
    (void)in_sizes; (void)n_in; (void)out_size; (void)ws_size;
    const float* image = (const float*)d_in[0];
    const float* su_s  = (const float*)d_in[1];
    const float* sv_s  = (const float*)d_in[2];
    const float* c_s   = (const float*)d_in[3];
    const float* w1_s  = (const float*)d_in[4];
    const float* b1_s  = (const float*)d_in[5];
    const float* w2_s  = (const float*)d_in[6];
    const float* b2_s  = (const float*)d_in[7];
    const float* w3_s  = (const float*)d_in[8];
    const float* b3_s  = (const float*)d_in[9];
    const float* fc_s  = (const float*)d_in[10];
    const float* su_i  = (const float*)d_in[11];
    const float* sv_i  = (const float*)d_in[12];
    const float* c_i   = (const float*)d_in[13];
    const float* w1_i  = (const float*)d_in[14];
    const float* b1_i  = (const float*)d_in[15];
    const float* w2_i  = (const float*)d_in[16];
    const float* b2_i  = (const float*)d_in[17];
    const float* w3_i  = (const float*)d_in[18];
    const float* b3_i  = (const float*)d_in[19];
    const float* fc_i  = (const float*)d_in[20];

    // ---- workspace: cumulative pointer arithmetic ONLY (r22 layout;
    //      hpart 48*45*4096 = 8,847,360 f < 11,075,584 reserved)
    float* W      = (float*)d_ws;
    float* hist   = W;                        // 178608 f
    float* hd     = hist + 178608;            // 144 (zeroed in prep)
    float* hd2    = hd + 144;                 // 144
    float* hsum3a = hd2 + 144;                // 48
    float* hsum3b = hsum3a + 48;              // 48
    float* msc    = hsum3b + 48;              // 144
    float* U      = msc + 144;
    float* hpart  = U;
    _Float16* o1h   = (_Float16*)(U + 11075584);
    _Float16* o2h   = o1h   + 1722368;
    _Float16* o3h   = o2h   + 802816;
    _Float16* fch   = o3h   + 1384448;
    _Float16* w2h_s = fch   + 1038336;
    _Float16* w3h_s = w2h_s + 294912;
    _Float16* w2h_i = w3h_s + 524288;
    _Float16* w3h_i = w2h_i + 294912;
    _Float16* w1h_s = w3h_i + 524288;
    _Float16* w1h_i = w1h_s + 12288;

    const int FCK = 86528;

    prep_weights<<<1024, 256, 0, stream>>>(w1_s, w1_i, w2_s, w3_s, w2_i, w3_i,
                                           fc_s, fc_i, w1h_s, w2h_s, fch, hd);

    // ================= sensor branch =================
    hist_mfma<<<dim3(48, HSP), 256, 0, stream>>>(image, su_s, sv_s, c_s, nullptr, hpart);
    reduce_hist<<<dim3(48, 8), 256, 0, stream>>>(hpart, hist, hsum3a);
    conv1_mfma<<<dim3(16, 27), 256, 0, stream>>>(hist, hsum3a, w1h_s, b1_s, o1h);
    conv_fused_mfma<128, 256, 3, 2, 29, 14, 64, 96, 32><<<dim3(16, 28), 256, 0, stream>>>(o1h, w2h_s, b2_s, o2h);
    conv_fused_mfma<256, 512, 2, 1, 14, 13, 64, 64, 32><<<dim3(16, 48), 256, 0, stream>>>(o2h, w3h_s, b3_s, o3h);
    fc_mfma<<<169, 256, 0, stream>>>(o3h, fch, hd, 9);
    build_m<<<1, 64, 0, stream>>>(hd, msc);

    // ================= illuminant branch =================
    hist_mfma<<<dim3(48, HSP), 256, 0, stream>>>(image, su_i, sv_i, c_i, msc, hpart);
    reduce_hist<<<dim3(48, 8), 256, 0, stream>>>(hpart, hist, hsum3b);
    conv1_mfma<<<dim3(16, 27), 256, 0, stream>>>(hist, hsum3b, w1h_i, b1_i, o1h);
    conv_fused_mfma<128, 256, 3, 2, 29, 14, 64, 96, 32><<<dim3(16, 28), 256, 0, stream>>>(o1h, w2h_i, b2_i, o2h);
    conv_fused_mfma<256, 512, 2, 1, 14, 13, 64, 64, 32><<<dim3(16, 48), 256, 0, stream>>>(o2h, w3h_i, b3_i, o3h);
    fc_mfma<<<169, 256, 0, stream>>>(o3h, fch + 9 * FCK, hd2, 3);
    final_est<<<1, 64, 0, stream>>>(msc, hd2, (float*)d_out);
}